// Round 8
// baseline (376.171 us; speedup 1.0000x reference)
//
#include <hip/hip_runtime.h>
#include <hip/hip_bf16.h>

// B=4, C=128, H=W=64 -> N=4096. ALL I/O FP32.
// Round 13: fused proj->flash->combine in ONE plain-launched kernel with a
// hand-rolled grid barrier (device-scope atomics in workspace, memset-zeroed
// per launch). R12's cooperative launch failed silently (absmax == max|ref|
// => out stayed zero); phase math was verified identical to the passing
// R11/R7 kernels, so this retries fusion with zero cooperative machinery.
// Co-residency: launch_bounds(256,2) x 256 CU = 512 blocks == grid, 64KB LDS
// -> 2 blocks/CU guaranteed; all blocks resident -> barrier deadlock-free.
// __threadfence() both sides of each barrier for cross-XCD L2 visibility.

#define BATCH 4
#define CH    128
#define NTOK  4096
#define TK    64
#define SCALE 0.08838834764831845f   // 1/sqrt(128)
#define LOG2E 1.4426950408889634f
#define MFIX  16.0f                  // fixed softmax offset (log2 units)
#define GRID  512

typedef __attribute__((ext_vector_type(8)))  short short8;
typedef __attribute__((ext_vector_type(4)))  float f32x4;
typedef __attribute__((ext_vector_type(16))) float f32x16;

static __device__ __forceinline__ unsigned short f2bf(float f) {
    __hip_bfloat16 h = (__hip_bfloat16)f;
    return *(const unsigned short*)&h;
}

static __device__ __forceinline__ unsigned cvt_pk_bf16(float lo, float hi) {
    unsigned r;
    asm("v_cvt_pk_bf16_f32 %0, %1, %2" : "=v"(r) : "v"(lo), "v"(hi));
    return r;
}

static __device__ __forceinline__ short8 pack_bf16x8(float4 a, float4 b) {
    union { unsigned u[4]; short8 s8; } f;
    f.u[0] = cvt_pk_bf16(a.x, a.y);
    f.u[1] = cvt_pk_bf16(a.z, a.w);
    f.u[2] = cvt_pk_bf16(b.x, b.y);
    f.u[3] = cvt_pk_bf16(b.z, b.w);
    return f.s8;
}

// Hand-rolled grid barrier. cnt/gen are zeroed by hipMemsetAsync each launch;
// each barrier instance uses its own pair (no reuse within a launch).
static __device__ __forceinline__ void grid_barrier(unsigned* cnt, unsigned* gen) {
    __syncthreads();
    __threadfence();    // release: this block's global stores visible device-wide
    if (threadIdx.x == 0) {
        unsigned prev = __hip_atomic_fetch_add(cnt, 1u, __ATOMIC_ACQ_REL,
                                               __HIP_MEMORY_SCOPE_AGENT);
        if (prev == GRID - 1) {
            __hip_atomic_store(gen, 1u, __ATOMIC_RELEASE,
                               __HIP_MEMORY_SCOPE_AGENT);
        } else {
            while (__hip_atomic_load(gen, __ATOMIC_ACQUIRE,
                                     __HIP_MEMORY_SCOPE_AGENT) == 0u) {}
        }
    }
    __syncthreads();
    __threadfence();    // acquire: drop stale cached lines before reading peers' data
}

// ======================= fused kernel (plain launch) =======================
__global__ __launch_bounds__(256, 2) void fused_kernel(
    const float* __restrict__ x,
    const float* __restrict__ Wq, const float* __restrict__ Wk,
    const float* __restrict__ Wv,
    const float* __restrict__ bq, const float* __restrict__ bk,
    const float* __restrict__ bv,
    unsigned short* __restrict__ q_ws, unsigned short* __restrict__ k_ws,
    unsigned short* __restrict__ vt_ws,
    float* __restrict__ out, float* __restrict__ Op, float* __restrict__ l_p,
    unsigned* __restrict__ bar)
{
    union SMem {
        struct { unsigned short Wl[CH * CH]; unsigned short XsT[64 * CH]; } p1;
        struct { unsigned short K[2][TK * CH]; unsigned short V[2][CH * TK]; } p2;
    };
    __shared__ __align__(16) SMem sm;

    const int t   = threadIdx.x;
    const int bid = blockIdx.x;

    // ===================== phase 1: QKV projection ========================
    {
        const int w    = t >> 6;
        const int lane = t & 63;
        const int quad = lane >> 4;
        const int c16  = lane & 15;
        const int nun  = (bid < 256) ? 2 : 1;

        for (int pu = 0; pu < nun; ++pu) {
            const int uid = (pu == 0) ? bid : 512 + bid;
            const int z   = uid >> 8;           // 0=Q, 1=K, 2=V
            const int rem = uid & 255;
            const int b   = rem >> 6;
            const int n0  = (rem & 63) * 64;
            const float* xb = x + (size_t)b * CH * NTOK;
            const float* wm = (z == 0) ? Wq : (z == 1) ? Wk : Wv;

            // cooperative W stage: 2048 8-float units, coalesced, swizzled
            #pragma unroll
            for (int i = 0; i < 8; ++i) {
                const int f   = i * 256 + t;
                const int row = f >> 4;
                const int u   = f & 15;
                const float* src = wm + f * 8;
                const float4 a = *(const float4*)src;
                const float4 c = *(const float4*)(src + 4);
                *(short8*)&sm.p1.Wl[row * CH + ((u ^ (row & 15)) << 3)] =
                    pack_bf16x8(a, c);
            }
            {   // stage x tile transposed: wave w covers channels 32w..32w+31
                const int tok = lane;
                #pragma unroll
                for (int cc = 0; cc < 4; ++cc) {
                    const int cb = 32 * w + 8 * cc;
                    float xv[8];
                    #pragma unroll
                    for (int j = 0; j < 8; ++j)
                        xv[j] = xb[(size_t)(cb + j) * NTOK + n0 + tok];
                    union { unsigned u[4]; short8 s8; } pk;
                    #pragma unroll
                    for (int j = 0; j < 4; ++j)
                        pk.u[j] = cvt_pk_bf16(xv[2 * j], xv[2 * j + 1]);
                    const int phys = ((cb >> 3) ^ (tok & 15));
                    *(short8*)&sm.p1.XsT[tok * CH + phys * 8] = pk.s8;
                }
            }
            __syncthreads();

            if (z < 2) {
                const float* bias = (z == 0) ? bq : bk;
                unsigned short* dst = (z == 0) ? q_ws : k_ws;
                const float mul = (z == 0) ? (SCALE * LOG2E) : 1.0f;

                short8 xa[4];
                #pragma unroll
                for (int ks = 0; ks < 4; ++ks)
                    xa[ks] = *(const short8*)
                        &sm.p1.XsT[(16 * w + c16) * CH + (((4 * ks + quad) ^ c16) << 3)];

                #pragma unroll
                for (int nt = 0; nt < 8; ++nt) {
                    f32x4 a = (f32x4){0.f, 0.f, 0.f, 0.f};
                    #pragma unroll
                    for (int ks = 0; ks < 4; ++ks) {
                        const short8 bf = *(const short8*)
                            &sm.p1.Wl[(16 * nt + c16) * CH + (((4 * ks + quad) ^ c16) << 3)];
                        a = __builtin_amdgcn_mfma_f32_16x16x32_bf16(xa[ks], bf, a, 0, 0, 0);
                    }
                    const float bvv = bias[16 * nt + c16];
                    #pragma unroll
                    for (int r = 0; r < 4; ++r) {
                        const int n = n0 + 16 * w + quad * 4 + r;
                        dst[((size_t)b * NTOK + n) * CH + 16 * nt + c16] =
                            f2bf((a[r] + bvv) * mul);
                    }
                }
            } else {
                #pragma unroll
                for (int nt = 0; nt < 4; ++nt) {
                    short8 xbf[4];
                    #pragma unroll
                    for (int ks = 0; ks < 4; ++ks)
                        xbf[ks] = *(const short8*)
                            &sm.p1.XsT[(16 * nt + c16) * CH + (((4 * ks + quad) ^ c16) << 3)];
                    #pragma unroll
                    for (int mt = 0; mt < 2; ++mt) {
                        const int crow16 = 16 * (2 * w + mt);
                        f32x4 acc = (f32x4){0.f, 0.f, 0.f, 0.f};
                        #pragma unroll
                        for (int ks = 0; ks < 4; ++ks) {
                            const short8 wva = *(const short8*)
                                &sm.p1.Wl[(crow16 + c16) * CH + (((4 * ks + quad) ^ c16) << 3)];
                            acc = __builtin_amdgcn_mfma_f32_16x16x32_bf16(wva, xbf[ks], acc, 0, 0, 0);
                        }
                        #pragma unroll
                        for (int r = 0; r < 4; ++r) {
                            const int crow = crow16 + quad * 4 + r;
                            vt_ws[((size_t)b * CH + crow) * NTOK + n0 + 16 * nt + c16] =
                                f2bf(acc[r] + bv[crow]);
                        }
                    }
                }
            }
            __syncthreads();   // safe to restage on next unit
        }
    }

    grid_barrier(bar + 0, bar + 1);

    // ===================== phase 2: flash attention (R7, SPLIT=4) =========
    {
        const int w    = t >> 6;
        const int lane = t & 63;
        const int half = lane >> 5;
        const int l32  = lane & 31;
        const int n0   = (bid & 31) * 128;
        const int jc   = (bid >> 5) & 3;
        const int b    = bid >> 7;
        const int jbeg = jc * (NTOK / 4);
        constexpr int NT = (NTOK / 4) / TK;

        const unsigned short* kg = k_ws  + (size_t)b * NTOK * CH;
        const unsigned short* vg = vt_ws + (size_t)b * CH * NTOK;

        short8 qa[8];
        {
            const unsigned short* qrow =
                q_ws + ((size_t)b * NTOK + n0 + 32 * w + l32) * CH;
            #pragma unroll
            for (int ks = 0; ks < 8; ++ks)
                qa[ks] = *(const short8*)(qrow + ks * 16 + half * 8);
        }

        f32x16 Oa[4];
        #pragma unroll
        for (int ct = 0; ct < 4; ++ct) Oa[ct] = (f32x16)(0.0f);
        float lsum = 0.f;

        const int krl = lane >> 4, ku = lane & 15;
        const int vcl = lane >> 3, vu = lane & 7;

        auto STAGE = [&](int buf, int jj) {
            #pragma unroll
            for (int ci = 0; ci < 4; ++ci) {
                const int row = 16 * w + 4 * ci + krl;
                const int g   = ku ^ (row & 15);
                const unsigned short* src = kg + (size_t)(jj + row) * CH + g * 8;
                __builtin_amdgcn_global_load_lds(
                    (const __attribute__((address_space(1))) void*)src,
                    (__attribute__((address_space(3))) void*)&sm.p2.K[buf][(16 * w + 4 * ci) * CH],
                    16, 0, 0);
            }
            #pragma unroll
            for (int ci = 0; ci < 4; ++ci) {
                const int c = 32 * w + 8 * ci + vcl;
                const int g = vu ^ (c & 7);
                const unsigned short* src = vg + (size_t)c * NTOK + jj + g * 8;
                __builtin_amdgcn_global_load_lds(
                    (const __attribute__((address_space(1))) void*)src,
                    (__attribute__((address_space(3))) void*)&sm.p2.V[buf][(32 * w + 8 * ci) * TK],
                    16, 0, 0);
            }
        };

        STAGE(0, jbeg);

        int j0 = jbeg;
        for (int tt = 0; tt < NT; ++tt, j0 += TK) {
            const int cur = tt & 1;
            if (tt + 1 < NT) {
                STAGE(cur ^ 1, j0 + TK);
                asm volatile("s_waitcnt vmcnt(8)" ::: "memory");
            } else {
                asm volatile("s_waitcnt vmcnt(0)" ::: "memory");
            }
            __builtin_amdgcn_sched_barrier(0);
            __builtin_amdgcn_s_barrier();
            __builtin_amdgcn_sched_barrier(0);

            const unsigned short* Kc = &sm.p2.K[cur][0];
            const unsigned short* Vc = &sm.p2.V[cur][0];

            f32x16 s[2];
            s[0] = (f32x16)(-MFIX);
            s[1] = (f32x16)(-MFIX);
            #pragma unroll
            for (int ks = 0; ks < 8; ++ks) {
                const int ph = (2 * ks + half) ^ (l32 & 15);
                const short8 kf0 = *(const short8*)&Kc[l32 * CH + ph * 8];
                const short8 kf1 = *(const short8*)&Kc[(32 + l32) * CH + ph * 8];
                s[0] = __builtin_amdgcn_mfma_f32_32x32x16_bf16(kf0, qa[ks], s[0], 0, 0, 0);
                s[1] = __builtin_amdgcn_mfma_f32_32x32x16_bf16(kf1, qa[ks], s[1], 0, 0, 0);
            }

            short8 pb[4];
            #pragma unroll
            for (int kt = 0; kt < 2; ++kt) {
                float p[16];
                #pragma unroll
                for (int r = 0; r < 16; ++r) p[r] = exp2f(s[kt][r]);
                float a0 = 0.f, a1 = 0.f, a2 = 0.f, a3 = 0.f;
                #pragma unroll
                for (int r = 0; r < 4; ++r) {
                    a0 += p[r]; a1 += p[4 + r]; a2 += p[8 + r]; a3 += p[12 + r];
                }
                lsum += (a0 + a1) + (a2 + a3);
                unsigned wd[8];
                #pragma unroll
                for (int i = 0; i < 8; ++i) wd[i] = cvt_pk_bf16(p[2 * i], p[2 * i + 1]);
                auto r02 = __builtin_amdgcn_permlane32_swap(wd[0], wd[2], false, false);
                auto r13 = __builtin_amdgcn_permlane32_swap(wd[1], wd[3], false, false);
                auto r46 = __builtin_amdgcn_permlane32_swap(wd[4], wd[6], false, false);
                auto r57 = __builtin_amdgcn_permlane32_swap(wd[5], wd[7], false, false);
                union { unsigned u[4]; short8 s8; } f0, f1;
                f0.u[0] = r02[0]; f0.u[1] = r13[0]; f0.u[2] = r02[1]; f0.u[3] = r13[1];
                f1.u[0] = r46[0]; f1.u[1] = r57[0]; f1.u[2] = r46[1]; f1.u[3] = r57[1];
                pb[2 * kt + 0] = f0.s8;
                pb[2 * kt + 1] = f1.s8;
            }

            #pragma unroll
            for (int ks2 = 0; ks2 < 4; ++ks2) {
                #pragma unroll
                for (int ct = 0; ct < 4; ++ct) {
                    const int ch = 32 * ct + l32;
                    const int ph = (2 * ks2 + half) ^ (ch & 7);
                    const short8 vf = *(const short8*)&Vc[ch * TK + ph * 8];
                    Oa[ct] = __builtin_amdgcn_mfma_f32_32x32x16_bf16(vf, pb[ks2], Oa[ct], 0, 0, 0);
                }
            }
            __builtin_amdgcn_sched_barrier(0);
            __builtin_amdgcn_s_barrier();
            __builtin_amdgcn_sched_barrier(0);
        }

        const float lt = lsum + __shfl_xor(lsum, 32);
        const int n = n0 + 32 * w + l32;
        const size_t chunk = (size_t)(b * 4 + jc);
        #pragma unroll
        for (int ct = 0; ct < 4; ++ct) {
            #pragma unroll
            for (int r = 0; r < 16; ++r) {
                const int c = 32 * ct + (r & 3) + 8 * (r >> 2) + 4 * half;
                Op[(chunk * CH + c) * NTOK + n] = Oa[ct][r];
            }
        }
        if (half == 0) l_p[chunk * NTOK + n] = lt;
    }

    grid_barrier(bar + 2, bar + 3);

    // ===================== phase 3: combine ===============================
    {
        const size_t nf4 = (size_t)BATCH * CH * NTOK / 4;   // 524288
        for (size_t fi = (size_t)bid * 256 + t; fi < nf4; fi += (size_t)GRID * 256) {
            const size_t g = fi * 4;
            const int b = (int)(g >> 19);                  // / (CH*NTOK)
            const int rem = (int)(g & ((CH * NTOK) - 1));
            const int c = rem >> 12;                       // / NTOK
            const int n = rem & (NTOK - 1);
            float4 acc = make_float4(0.f, 0.f, 0.f, 0.f);
            float4 den = make_float4(0.f, 0.f, 0.f, 0.f);
            #pragma unroll
            for (int j = 0; j < 4; ++j) {
                const size_t chunk = (size_t)(b * 4 + j);
                const float4 o = *(const float4*)&Op[(chunk * CH + c) * NTOK + n];
                const float4 d = *(const float4*)&l_p[chunk * NTOK + n];
                acc.x += o.x; acc.y += o.y; acc.z += o.z; acc.w += o.w;
                den.x += d.x; den.y += d.y; den.z += d.z; den.w += d.w;
            }
            float4 r;
            r.x = acc.x / den.x; r.y = acc.y / den.y;
            r.z = acc.z / den.z; r.w = acc.w / den.w;
            *(float4*)&out[g] = r;
        }
    }
}

// ======================= fallback kernels (small ws) =======================
__global__ __launch_bounds__(256) void proj_mfma_kernel(
    const float* __restrict__ x,
    const float* __restrict__ Wq, const float* __restrict__ Wk,
    const float* __restrict__ Wv,
    const float* __restrict__ bq, const float* __restrict__ bk,
    const float* __restrict__ bv,
    unsigned short* __restrict__ q_ws, unsigned short* __restrict__ k_ws,
    unsigned short* __restrict__ vt_ws)
{
    __shared__ __align__(16) unsigned short Wl[CH * CH];
    __shared__ __align__(16) unsigned short XsT[64 * CH];

    const int t    = threadIdx.x;
    const int w    = t >> 6;
    const int lane = t & 63;
    const int quad = lane >> 4;
    const int c16  = lane & 15;
    const int n0   = blockIdx.x * 64;
    const int b    = blockIdx.y;
    const int z    = blockIdx.z;
    const float* xb = x + (size_t)b * CH * NTOK;
    const float* wm = (z == 0) ? Wq : (z == 1) ? Wk : Wv;

    #pragma unroll
    for (int i = 0; i < 8; ++i) {
        const int f   = i * 256 + t;
        const int row = f >> 4;
        const int u   = f & 15;
        const float* src = wm + f * 8;
        const float4 a = *(const float4*)src;
        const float4 c = *(const float4*)(src + 4);
        *(short8*)&Wl[row * CH + ((u ^ (row & 15)) << 3)] = pack_bf16x8(a, c);
    }
    {
        const int tok = lane;
        #pragma unroll
        for (int cc = 0; cc < 4; ++cc) {
            const int cb = 32 * w + 8 * cc;
            float xv[8];
            #pragma unroll
            for (int j = 0; j < 8; ++j)
                xv[j] = xb[(size_t)(cb + j) * NTOK + n0 + tok];
            union { unsigned u[4]; short8 s8; } pk;
            #pragma unroll
            for (int j = 0; j < 4; ++j)
                pk.u[j] = cvt_pk_bf16(xv[2 * j], xv[2 * j + 1]);
            const int phys = ((cb >> 3) ^ (tok & 15));
            *(short8*)&XsT[tok * CH + phys * 8] = pk.s8;
        }
    }
    __syncthreads();

    if (z < 2) {
        const float* bias = (z == 0) ? bq : bk;
        unsigned short* dst = (z == 0) ? q_ws : k_ws;
        const float mul = (z == 0) ? (SCALE * LOG2E) : 1.0f;
        short8 xa[4];
        #pragma unroll
        for (int ks = 0; ks < 4; ++ks)
            xa[ks] = *(const short8*)&XsT[(16 * w + c16) * CH + (((4 * ks + quad) ^ c16) << 3)];
        #pragma unroll
        for (int nt = 0; nt < 8; ++nt) {
            f32x4 a = (f32x4){0.f, 0.f, 0.f, 0.f};
            #pragma unroll
            for (int ks = 0; ks < 4; ++ks) {
                const short8 bf = *(const short8*)
                    &Wl[(16 * nt + c16) * CH + (((4 * ks + quad) ^ c16) << 3)];
                a = __builtin_amdgcn_mfma_f32_16x16x32_bf16(xa[ks], bf, a, 0, 0, 0);
            }
            const float bvv = bias[16 * nt + c16];
            #pragma unroll
            for (int r = 0; r < 4; ++r) {
                const int n = n0 + 16 * w + quad * 4 + r;
                dst[((size_t)b * NTOK + n) * CH + 16 * nt + c16] =
                    f2bf((a[r] + bvv) * mul);
            }
        }
    } else {
        #pragma unroll
        for (int nt = 0; nt < 4; ++nt) {
            short8 xbf[4];
            #pragma unroll
            for (int ks = 0; ks < 4; ++ks)
                xbf[ks] = *(const short8*)&XsT[(16 * nt + c16) * CH + (((4 * ks + quad) ^ c16) << 3)];
            #pragma unroll
            for (int mt = 0; mt < 2; ++mt) {
                const int crow16 = 16 * (2 * w + mt);
                f32x4 acc = (f32x4){0.f, 0.f, 0.f, 0.f};
                #pragma unroll
                for (int ks = 0; ks < 4; ++ks) {
                    const short8 wva = *(const short8*)
                        &Wl[(crow16 + c16) * CH + (((4 * ks + quad) ^ c16) << 3)];
                    acc = __builtin_amdgcn_mfma_f32_16x16x32_bf16(wva, xbf[ks], acc, 0, 0, 0);
                }
                #pragma unroll
                for (int r = 0; r < 4; ++r) {
                    const int crow = crow16 + quad * 4 + r;
                    vt_ws[((size_t)b * CH + crow) * NTOK + n0 + 16 * nt + c16] =
                        f2bf(acc[r] + bv[crow]);
                }
            }
        }
    }
}

__global__ __launch_bounds__(256, 2) void flash_attn_s1(
    const unsigned short* __restrict__ q_ws,
    const unsigned short* __restrict__ k_ws,
    const unsigned short* __restrict__ vt_ws,
    float* __restrict__ out)
{
    __shared__ __align__(16) unsigned short KsU[2][TK * CH];
    __shared__ __align__(16) unsigned short VtU[2][CH * TK];

    const int t    = threadIdx.x;
    const int w    = t >> 6;
    const int lane = t & 63;
    const int half = lane >> 5;
    const int l32  = lane & 31;
    const int b    = blockIdx.z;
    const int n0   = blockIdx.x * 128;
    constexpr int NT = NTOK / TK;

    const unsigned short* kg = k_ws  + (size_t)b * NTOK * CH;
    const unsigned short* vg = vt_ws + (size_t)b * CH * NTOK;

    short8 qa[8];
    {
        const unsigned short* qrow =
            q_ws + ((size_t)b * NTOK + n0 + 32 * w + l32) * CH;
        #pragma unroll
        for (int ks = 0; ks < 8; ++ks)
            qa[ks] = *(const short8*)(qrow + ks * 16 + half * 8);
    }
    f32x16 Oa[4];
    #pragma unroll
    for (int ct = 0; ct < 4; ++ct) Oa[ct] = (f32x16)(0.0f);
    float lsum = 0.f;

    const int krl = lane >> 4, ku = lane & 15;
    const int vcl = lane >> 3, vu = lane & 7;

    auto STAGE = [&](int buf, int jj) {
        #pragma unroll
        for (int ci = 0; ci < 4; ++ci) {
            const int row = 16 * w + 4 * ci + krl;
            const int g   = ku ^ (row & 15);
            const unsigned short* src = kg + (size_t)(jj + row) * CH + g * 8;
            __builtin_amdgcn_global_load_lds(
                (const __attribute__((address_space(1))) void*)src,
                (__attribute__((address_space(3))) void*)&KsU[buf][(16 * w + 4 * ci) * CH],
                16, 0, 0);
        }
        #pragma unroll
        for (int ci = 0; ci < 4; ++ci) {
            const int c = 32 * w + 8 * ci + vcl;
            const int g = vu ^ (c & 7);
            const unsigned short* src = vg + (size_t)c * NTOK + jj + g * 8;
            __builtin_amdgcn_global_load_lds(
                (const __attribute__((address_space(1))) void*)src,
                (__attribute__((address_space(3))) void*)&VtU[buf][(32 * w + 8 * ci) * TK],
                16, 0, 0);
        }
    };

    STAGE(0, 0);
    int j0 = 0;
    for (int tt = 0; tt < NT; ++tt, j0 += TK) {
        const int cur = tt & 1;
        if (tt + 1 < NT) {
            STAGE(cur ^ 1, j0 + TK);
            asm volatile("s_waitcnt vmcnt(8)" ::: "memory");
        } else {
            asm volatile("s_waitcnt vmcnt(0)" ::: "memory");
        }
        __builtin_amdgcn_sched_barrier(0);
        __builtin_amdgcn_s_barrier();
        __builtin_amdgcn_sched_barrier(0);

        const unsigned short* Kc = &KsU[cur][0];
        const unsigned short* Vc = &VtU[cur][0];

        f32x16 s[2];
        s[0] = (f32x16)(-MFIX);
        s[1] = (f32x16)(-MFIX);
        #pragma unroll
        for (int ks = 0; ks < 8; ++ks) {
            const int ph = (2 * ks + half) ^ (l32 & 15);
            const short8 kf0 = *(const short8*)&Kc[l32 * CH + ph * 8];
            const short8 kf1 = *(const short8*)&Kc[(32 + l32) * CH + ph * 8];
            s[0] = __builtin_amdgcn_mfma_f32_32x32x16_bf16(kf0, qa[ks], s[0], 0, 0, 0);
            s[1] = __builtin_amdgcn_mfma_f32_32x32x16_bf16(kf1, qa[ks], s[1], 0, 0, 0);
        }
        short8 pb[4];
        #pragma unroll
        for (int kt = 0; kt < 2; ++kt) {
            float p[16];
            #pragma unroll
            for (int r = 0; r < 16; ++r) p[r] = exp2f(s[kt][r]);
            float a0 = 0.f, a1 = 0.f, a2 = 0.f, a3 = 0.f;
            #pragma unroll
            for (int r = 0; r < 4; ++r) {
                a0 += p[r]; a1 += p[4 + r]; a2 += p[8 + r]; a3 += p[12 + r];
            }
            lsum += (a0 + a1) + (a2 + a3);
            unsigned wd[8];
            #pragma unroll
            for (int i = 0; i < 8; ++i) wd[i] = cvt_pk_bf16(p[2 * i], p[2 * i + 1]);
            auto r02 = __builtin_amdgcn_permlane32_swap(wd[0], wd[2], false, false);
            auto r13 = __builtin_amdgcn_permlane32_swap(wd[1], wd[3], false, false);
            auto r46 = __builtin_amdgcn_permlane32_swap(wd[4], wd[6], false, false);
            auto r57 = __builtin_amdgcn_permlane32_swap(wd[5], wd[7], false, false);
            union { unsigned u[4]; short8 s8; } f0, f1;
            f0.u[0] = r02[0]; f0.u[1] = r13[0]; f0.u[2] = r02[1]; f0.u[3] = r13[1];
            f1.u[0] = r46[0]; f1.u[1] = r57[0]; f1.u[2] = r46[1]; f1.u[3] = r57[1];
            pb[2 * kt + 0] = f0.s8;
            pb[2 * kt + 1] = f1.s8;
        }
        #pragma unroll
        for (int ks2 = 0; ks2 < 4; ++ks2) {
            #pragma unroll
            for (int ct = 0; ct < 4; ++ct) {
                const int ch = 32 * ct + l32;
                const int ph = (2 * ks2 + half) ^ (ch & 7);
                const short8 vf = *(const short8*)&Vc[ch * TK + ph * 8];
                Oa[ct] = __builtin_amdgcn_mfma_f32_32x32x16_bf16(vf, pb[ks2], Oa[ct], 0, 0, 0);
            }
        }
        __builtin_amdgcn_sched_barrier(0);
        __builtin_amdgcn_s_barrier();
        __builtin_amdgcn_sched_barrier(0);
    }

    const float lt = lsum + __shfl_xor(lsum, 32);
    const int n = n0 + 32 * w + l32;
    const float inv = 1.0f / lt;
    #pragma unroll
    for (int ct = 0; ct < 4; ++ct) {
        #pragma unroll
        for (int r = 0; r < 16; ++r) {
            const int c = 32 * ct + (r & 3) + 8 * (r >> 2) + 4 * half;
            out[((size_t)b * CH + c) * NTOK + n] = Oa[ct][r] * inv;
        }
    }
}

extern "C" void kernel_launch(void* const* d_in, const int* in_sizes, int n_in,
                              void* d_out, int out_size, void* d_ws, size_t ws_size,
                              hipStream_t stream) {
    const float* x  = (const float*)d_in[0];
    const float* Wq = (const float*)d_in[1];
    const float* bq = (const float*)d_in[2];
    const float* Wk = (const float*)d_in[3];
    const float* bk = (const float*)d_in[4];
    const float* Wv = (const float*)d_in[5];
    const float* bv = (const float*)d_in[6];
    float* out = (float*)d_out;

    const size_t QKV = (size_t)BATCH * NTOK * CH;
    unsigned short* q_ws  = (unsigned short*)d_ws;
    unsigned short* k_ws  = q_ws + QKV;
    unsigned short* vt_ws = k_ws + QKV;
    float* Op = (float*)(vt_ws + QKV);
    float* l_p = Op + (size_t)4 * BATCH * NTOK * CH;
    unsigned* bar = (unsigned*)(l_p + (size_t)4 * BATCH * NTOK);

    const size_t baseBytes = 3 * QKV * 2;
    const size_t need4 = baseBytes
                       + (size_t)4 * BATCH * NTOK * (CH * 4 + 4)
                       + 64;  // barrier state

    if (ws_size >= need4) {
        hipMemsetAsync(bar, 0, 4 * sizeof(unsigned), stream);
        fused_kernel<<<GRID, 256, 0, stream>>>(x, Wq, Wk, Wv, bq, bk, bv,
                                               q_ws, k_ws, vt_ws,
                                               out, Op, l_p, bar);
    } else {
        dim3 gp(NTOK / 64, BATCH, 3);
        proj_mfma_kernel<<<gp, 256, 0, stream>>>(x, Wq, Wk, Wv, bq, bk, bv,
                                                 q_ws, k_ws, vt_ws);
        dim3 ga(NTOK / 128, 1, BATCH);
        flash_attn_s1<<<ga, 256, 0, stream>>>(q_ws, k_ws, vt_ws, out);
    }
}

// Round 9
// 215.657 us; speedup vs baseline: 1.7443x; 1.7443x over previous
//
#include <hip/hip_runtime.h>
#include <hip/hip_bf16.h>

// B=4, C=128, H=W=64 -> N=4096. ALL I/O FP32.
// Round 14: back to 3 plain kernels (R13 proved overhead is ~40us FIXED, not
// per-launch; fusion via spin barrier = 336us, abandoned). Flash rebuilt with
// q-register-blocking: each wave owns 64 q-rows (2 q-sets) x all 128 ch, so
// every kf/vf LDS fragment feeds TWO MFMAs -> LDS bytes/MFMA halved (flash was
// LDS-read-bound: 1KB/MFMA vs 128-256 B/cy supply -> MfmaUtil 25%).
// No duplicated softmax (R6's mistake). Register budget engineered for the
// 256-VGPR cap of launch_bounds(256,2): Oa 128 + qa 64 + s 32 (kt-split: only
// one kt's S live) + pb 32 + temps ~= 250. SPLIT=8 -> 16x8x4 = 512 blocks =
// 2/CU. proj/combine = R11's proven versions.

#define BATCH 4
#define CH    128
#define NTOK  4096
#define TK    64
#define SCALE 0.08838834764831845f   // 1/sqrt(128)
#define LOG2E 1.4426950408889634f
#define MFIX  16.0f                  // fixed softmax offset (log2 units)

typedef __attribute__((ext_vector_type(8)))  short short8;
typedef __attribute__((ext_vector_type(4)))  float f32x4;
typedef __attribute__((ext_vector_type(16))) float f32x16;

static __device__ __forceinline__ unsigned short f2bf(float f) {
    __hip_bfloat16 h = (__hip_bfloat16)f;
    return *(const unsigned short*)&h;
}

static __device__ __forceinline__ unsigned cvt_pk_bf16(float lo, float hi) {
    unsigned r;
    asm("v_cvt_pk_bf16_f32 %0, %1, %2" : "=v"(r) : "v"(lo), "v"(hi));
    return r;
}

static __device__ __forceinline__ short8 pack_bf16x8(float4 a, float4 b) {
    union { unsigned u[4]; short8 s8; } f;
    f.u[0] = cvt_pk_bf16(a.x, a.y);
    f.u[1] = cvt_pk_bf16(a.z, a.w);
    f.u[2] = cvt_pk_bf16(b.x, b.y);
    f.u[3] = cvt_pk_bf16(b.z, b.w);
    return f.s8;
}

// ---------------- MFMA QKV projection (R11, proven) ------------------------
__global__ __launch_bounds__(256) void proj_mfma_kernel(
    const float* __restrict__ x,
    const float* __restrict__ Wq, const float* __restrict__ Wk,
    const float* __restrict__ Wv,
    const float* __restrict__ bq, const float* __restrict__ bk,
    const float* __restrict__ bv,
    unsigned short* __restrict__ q_ws, unsigned short* __restrict__ k_ws,
    unsigned short* __restrict__ vt_ws)
{
    __shared__ __align__(16) unsigned short Wl[CH * CH];   // 32 KB, swizzled
    __shared__ __align__(16) unsigned short XsT[64 * CH];  // 16 KB, swizzled

    const int t    = threadIdx.x;
    const int w    = t >> 6;
    const int lane = t & 63;
    const int quad = lane >> 4;
    const int c16  = lane & 15;
    const int n0   = blockIdx.x * 64;
    const int b    = blockIdx.y;
    const int z    = blockIdx.z;          // 0=Q, 1=K, 2=V
    const float* xb = x + (size_t)b * CH * NTOK;
    const float* wm = (z == 0) ? Wq : (z == 1) ? Wk : Wv;

    #pragma unroll
    for (int i = 0; i < 8; ++i) {
        const int f   = i * 256 + t;
        const int row = f >> 4;
        const int u   = f & 15;
        const float* src = wm + f * 8;
        const float4 a = *(const float4*)src;
        const float4 c = *(const float4*)(src + 4);
        *(short8*)&Wl[row * CH + ((u ^ (row & 15)) << 3)] = pack_bf16x8(a, c);
    }
    {
        const int tok = lane;
        #pragma unroll
        for (int cc = 0; cc < 4; ++cc) {
            const int cb = 32 * w + 8 * cc;
            float xv[8];
            #pragma unroll
            for (int j = 0; j < 8; ++j)
                xv[j] = xb[(size_t)(cb + j) * NTOK + n0 + tok];
            union { unsigned u[4]; short8 s8; } pk;
            #pragma unroll
            for (int j = 0; j < 4; ++j)
                pk.u[j] = cvt_pk_bf16(xv[2 * j], xv[2 * j + 1]);
            const int phys = ((cb >> 3) ^ (tok & 15));
            *(short8*)&XsT[tok * CH + phys * 8] = pk.s8;
        }
    }
    __syncthreads();

    if (z < 2) {
        const float* bias = (z == 0) ? bq : bk;
        unsigned short* dst = (z == 0) ? q_ws : k_ws;
        const float mul = (z == 0) ? (SCALE * LOG2E) : 1.0f;
        short8 xa[4];
        #pragma unroll
        for (int ks = 0; ks < 4; ++ks)
            xa[ks] = *(const short8*)&XsT[(16 * w + c16) * CH + (((4 * ks + quad) ^ c16) << 3)];
        #pragma unroll
        for (int nt = 0; nt < 8; ++nt) {
            f32x4 a = (f32x4){0.f, 0.f, 0.f, 0.f};
            #pragma unroll
            for (int ks = 0; ks < 4; ++ks) {
                const short8 bf = *(const short8*)
                    &Wl[(16 * nt + c16) * CH + (((4 * ks + quad) ^ c16) << 3)];
                a = __builtin_amdgcn_mfma_f32_16x16x32_bf16(xa[ks], bf, a, 0, 0, 0);
            }
            const float bvv = bias[16 * nt + c16];
            #pragma unroll
            for (int r = 0; r < 4; ++r) {
                const int n = n0 + 16 * w + quad * 4 + r;
                dst[((size_t)b * NTOK + n) * CH + 16 * nt + c16] =
                    f2bf((a[r] + bvv) * mul);
            }
        }
    } else {
        #pragma unroll
        for (int nt = 0; nt < 4; ++nt) {
            short8 xbf[4];
            #pragma unroll
            for (int ks = 0; ks < 4; ++ks)
                xbf[ks] = *(const short8*)&XsT[(16 * nt + c16) * CH + (((4 * ks + quad) ^ c16) << 3)];
            #pragma unroll
            for (int mt = 0; mt < 2; ++mt) {
                const int crow16 = 16 * (2 * w + mt);
                f32x4 acc = (f32x4){0.f, 0.f, 0.f, 0.f};
                #pragma unroll
                for (int ks = 0; ks < 4; ++ks) {
                    const short8 wva = *(const short8*)
                        &Wl[(crow16 + c16) * CH + (((4 * ks + quad) ^ c16) << 3)];
                    acc = __builtin_amdgcn_mfma_f32_16x16x32_bf16(wva, xbf[ks], acc, 0, 0, 0);
                }
                #pragma unroll
                for (int r = 0; r < 4; ++r) {
                    const int crow = crow16 + quad * 4 + r;
                    vt_ws[((size_t)b * CH + crow) * NTOK + n0 + 16 * nt + c16] =
                        f2bf(acc[r] + bv[crow]);
                }
            }
        }
    }
}

// ---------------- q-blocked split-KV MFMA flash attention ------------------
// 4 waves x 64 q-rows (2 q-sets of 32) x all 128 ch. Block = 256 q-rows.
// Per tile per wave: 16 kf reads -> 32 QK^T MFMA; 16 vf reads -> 32 PV MFMA.
// (2x fragment reuse vs R7; LDS-read-bound -> balance point.)
template <int SPLIT>
__global__ __launch_bounds__(256, 2) void flash_attn_mfma(
    const unsigned short* __restrict__ q_ws,
    const unsigned short* __restrict__ k_ws,
    const unsigned short* __restrict__ vt_ws,
    float* __restrict__ out,
    float* __restrict__ Op, float* __restrict__ l_p)
{
    __shared__ __align__(16) unsigned short KsU[2][TK * CH];  // 2 x 16 KB
    __shared__ __align__(16) unsigned short VtU[2][CH * TK];  // 2 x 16 KB

    const int t    = threadIdx.x;
    const int w    = t >> 6;
    const int lane = t & 63;
    const int half = lane >> 5;
    const int l32  = lane & 31;
    const int jc   = blockIdx.y;
    const int b    = blockIdx.z;
    const int n0   = blockIdx.x * 256;
    const int jbeg = jc * (NTOK / SPLIT);
    constexpr int NT = (NTOK / SPLIT) / TK;

    const unsigned short* kg = k_ws  + (size_t)b * NTOK * CH;
    const unsigned short* vg = vt_ws + (size_t)b * CH * NTOK;

    // Q B-frags, 2 q-sets: B[k=ch][n=q=l32]
    short8 qa[2][8];
    #pragma unroll
    for (int qs = 0; qs < 2; ++qs) {
        const unsigned short* qrow =
            q_ws + ((size_t)b * NTOK + n0 + 64 * w + 32 * qs + l32) * CH;
        #pragma unroll
        for (int ks = 0; ks < 8; ++ks)
            qa[qs][ks] = *(const short8*)(qrow + ks * 16 + half * 8);
    }

    f32x16 Oa[2][4];  // O^T tiles per q-set, D[m=ch 32ct..][n=q]
    #pragma unroll
    for (int qs = 0; qs < 2; ++qs)
        #pragma unroll
        for (int ct = 0; ct < 4; ++ct) Oa[qs][ct] = (f32x16)(0.0f);
    float lsum[2] = {0.f, 0.f};

    const int krl = lane >> 4, ku = lane & 15;
    const int vcl = lane >> 3, vu = lane & 7;

    auto STAGE = [&](int buf, int jj) {
        #pragma unroll
        for (int ci = 0; ci < 4; ++ci) {
            const int row = 16 * w + 4 * ci + krl;
            const int g   = ku ^ (row & 15);
            const unsigned short* src = kg + (size_t)(jj + row) * CH + g * 8;
            __builtin_amdgcn_global_load_lds(
                (const __attribute__((address_space(1))) void*)src,
                (__attribute__((address_space(3))) void*)&KsU[buf][(16 * w + 4 * ci) * CH],
                16, 0, 0);
        }
        #pragma unroll
        for (int ci = 0; ci < 4; ++ci) {
            const int c = 32 * w + 8 * ci + vcl;
            const int g = vu ^ (c & 7);
            const unsigned short* src = vg + (size_t)c * NTOK + jj + g * 8;
            __builtin_amdgcn_global_load_lds(
                (const __attribute__((address_space(1))) void*)src,
                (__attribute__((address_space(3))) void*)&VtU[buf][(32 * w + 8 * ci) * TK],
                16, 0, 0);
        }
    };

    STAGE(0, jbeg);   // 8 loads/wave in flight

    int j0 = jbeg;
    for (int tt = 0; tt < NT; ++tt, j0 += TK) {
        const int cur = tt & 1;
        if (tt + 1 < NT) {
            STAGE(cur ^ 1, j0 + TK);                         // prefetch next
            asm volatile("s_waitcnt vmcnt(8)" ::: "memory"); // own cur loads done
        } else {
            asm volatile("s_waitcnt vmcnt(0)" ::: "memory");
        }
        __builtin_amdgcn_sched_barrier(0);
        __builtin_amdgcn_s_barrier();                        // all waves' cur landed
        __builtin_amdgcn_sched_barrier(0);

        const unsigned short* Kc = &KsU[cur][0];
        const unsigned short* Vc = &VtU[cur][0];

        // --- S^T = K Q^T - MFIX, kt-split (only one kt's S live) ---
        short8 pb[2][4];  // [qs][k-chunk] PV B-frags
        #pragma unroll
        for (int kt = 0; kt < 2; ++kt) {
            f32x16 s[2];
            s[0] = (f32x16)(-MFIX);
            s[1] = (f32x16)(-MFIX);
            #pragma unroll
            for (int ks = 0; ks < 8; ++ks) {
                const int ph = (2 * ks + half) ^ (l32 & 15);
                const short8 kf = *(const short8*)&Kc[(32 * kt + l32) * CH + ph * 8];
                s[0] = __builtin_amdgcn_mfma_f32_32x32x16_bf16(kf, qa[0][ks], s[0], 0, 0, 0);
                s[1] = __builtin_amdgcn_mfma_f32_32x32x16_bf16(kf, qa[1][ks], s[1], 0, 0, 0);
            }
            // --- P = exp2(S) in-register; pack via cvt_pk + permlane32_swap ---
            #pragma unroll
            for (int qs = 0; qs < 2; ++qs) {
                float p[16];
                #pragma unroll
                for (int r = 0; r < 16; ++r) p[r] = exp2f(s[qs][r]);
                float a0 = 0.f, a1 = 0.f, a2 = 0.f, a3 = 0.f;
                #pragma unroll
                for (int r = 0; r < 4; ++r) {
                    a0 += p[r]; a1 += p[4 + r]; a2 += p[8 + r]; a3 += p[12 + r];
                }
                lsum[qs] += (a0 + a1) + (a2 + a3);
                unsigned wd[8];
                #pragma unroll
                for (int i = 0; i < 8; ++i) wd[i] = cvt_pk_bf16(p[2 * i], p[2 * i + 1]);
                auto r02 = __builtin_amdgcn_permlane32_swap(wd[0], wd[2], false, false);
                auto r13 = __builtin_amdgcn_permlane32_swap(wd[1], wd[3], false, false);
                auto r46 = __builtin_amdgcn_permlane32_swap(wd[4], wd[6], false, false);
                auto r57 = __builtin_amdgcn_permlane32_swap(wd[5], wd[7], false, false);
                union { unsigned u[4]; short8 s8; } f0, f1;
                f0.u[0] = r02[0]; f0.u[1] = r13[0]; f0.u[2] = r02[1]; f0.u[3] = r13[1];
                f1.u[0] = r46[0]; f1.u[1] = r57[0]; f1.u[2] = r46[1]; f1.u[3] = r57[1];
                pb[qs][2 * kt + 0] = f0.s8;
                pb[qs][2 * kt + 1] = f1.s8;
            }
        }

        // --- O^T += V^T P^T : each vf read feeds both q-sets ---
        #pragma unroll
        for (int ks2 = 0; ks2 < 4; ++ks2) {
            #pragma unroll
            for (int ct = 0; ct < 4; ++ct) {
                const int ch = 32 * ct + l32;
                const int ph = (2 * ks2 + half) ^ (ch & 7);
                const short8 vf = *(const short8*)&Vc[ch * TK + ph * 8];
                Oa[0][ct] = __builtin_amdgcn_mfma_f32_32x32x16_bf16(vf, pb[0][ks2], Oa[0][ct], 0, 0, 0);
                Oa[1][ct] = __builtin_amdgcn_mfma_f32_32x32x16_bf16(vf, pb[1][ks2], Oa[1][ct], 0, 0, 0);
            }
        }
        __builtin_amdgcn_sched_barrier(0);
        __builtin_amdgcn_s_barrier();   // all waves done reading cur before re-stage
        __builtin_amdgcn_sched_barrier(0);
    }

    // --- epilogue: l lane-local; stores coalesced (lane = token) ---
    float lt[2];
    #pragma unroll
    for (int qs = 0; qs < 2; ++qs)
        lt[qs] = lsum[qs] + __shfl_xor(lsum[qs], 32);

    if constexpr (SPLIT == 1) {
        #pragma unroll
        for (int qs = 0; qs < 2; ++qs) {
            const float inv = 1.0f / lt[qs];
            const int n = n0 + 64 * w + 32 * qs + l32;
            #pragma unroll
            for (int ct = 0; ct < 4; ++ct) {
                #pragma unroll
                for (int r = 0; r < 16; ++r) {
                    const int c = 32 * ct + (r & 3) + 8 * (r >> 2) + 4 * half;
                    out[((size_t)b * CH + c) * NTOK + n] = Oa[qs][ct][r] * inv;
                }
            }
        }
    } else {
        const size_t chunk = (size_t)(b * SPLIT + jc);
        #pragma unroll
        for (int qs = 0; qs < 2; ++qs) {
            const int n = n0 + 64 * w + 32 * qs + l32;
            #pragma unroll
            for (int ct = 0; ct < 4; ++ct) {
                #pragma unroll
                for (int r = 0; r < 16; ++r) {
                    const int c = 32 * ct + (r & 3) + 8 * (r >> 2) + 4 * half;
                    Op[(chunk * CH + c) * NTOK + n] = Oa[qs][ct][r];
                }
            }
            if (half == 0) l_p[chunk * NTOK + n] = lt[qs];
        }
    }
}

// ---------------- combine partials: Op layout [chunk][C][N], coalesced -----
template <int SPLIT>
__global__ __launch_bounds__(256) void combine_kernel(
    const float* __restrict__ Op, const float* __restrict__ l_p,
    float* __restrict__ out)
{
    const int b = blockIdx.y;
    const size_t idx = ((size_t)blockIdx.x * 256 + threadIdx.x) * 4;  // in C*N
    const int c = (int)(idx >> 12);           // / NTOK
    const int n = (int)(idx & (NTOK - 1));
    float4 acc = make_float4(0.f, 0.f, 0.f, 0.f);
    float4 den = make_float4(0.f, 0.f, 0.f, 0.f);
    #pragma unroll
    for (int j = 0; j < SPLIT; ++j) {
        const size_t chunk = (size_t)(b * SPLIT + j);
        const float4 o = *(const float4*)&Op[(chunk * CH + c) * NTOK + n];
        const float4 d = *(const float4*)&l_p[chunk * NTOK + n];
        acc.x += o.x; acc.y += o.y; acc.z += o.z; acc.w += o.w;
        den.x += d.x; den.y += d.y; den.z += d.z; den.w += d.w;
    }
    float4 r;
    r.x = acc.x / den.x; r.y = acc.y / den.y;
    r.z = acc.z / den.z; r.w = acc.w / den.w;
    *(float4*)&out[((size_t)b * CH * NTOK) + idx] = r;
}

extern "C" void kernel_launch(void* const* d_in, const int* in_sizes, int n_in,
                              void* d_out, int out_size, void* d_ws, size_t ws_size,
                              hipStream_t stream) {
    const float* x  = (const float*)d_in[0];
    const float* Wq = (const float*)d_in[1];
    const float* bq = (const float*)d_in[2];
    const float* Wk = (const float*)d_in[3];
    const float* bk = (const float*)d_in[4];
    const float* Wv = (const float*)d_in[5];
    const float* bv = (const float*)d_in[6];
    float* out = (float*)d_out;

    const size_t QKV = (size_t)BATCH * NTOK * CH;
    unsigned short* q_ws  = (unsigned short*)d_ws;
    unsigned short* k_ws  = q_ws + QKV;
    unsigned short* vt_ws = k_ws + QKV;
    float* Op = (float*)(vt_ws + QKV);

    const size_t baseBytes = 3 * QKV * 2;
    auto needBytes = [&](size_t S) {
        return baseBytes + S * BATCH * NTOK * (size_t)(CH * 4 + 4);
    };

    dim3 gp(NTOK / 64, BATCH, 3);
    proj_mfma_kernel<<<gp, 256, 0, stream>>>(x, Wq, Wk, Wv, bq, bk, bv,
                                             q_ws, k_ws, vt_ws);

    dim3 gc(CH * NTOK / 1024, BATCH);
    if (ws_size >= needBytes(8)) {
        float* l_p = Op + (size_t)8 * BATCH * NTOK * CH;
        dim3 ga(NTOK / 256, 8, BATCH);
        flash_attn_mfma<8><<<ga, 256, 0, stream>>>(q_ws, k_ws, vt_ws, out, Op, l_p);
        combine_kernel<8><<<gc, 256, 0, stream>>>(Op, l_p, out);
    } else if (ws_size >= needBytes(4)) {
        float* l_p = Op + (size_t)4 * BATCH * NTOK * CH;
        dim3 ga(NTOK / 256, 4, BATCH);
        flash_attn_mfma<4><<<ga, 256, 0, stream>>>(q_ws, k_ws, vt_ws, out, Op, l_p);
        combine_kernel<4><<<gc, 256, 0, stream>>>(Op, l_p, out);
    } else {
        dim3 ga(NTOK / 256, 1, BATCH);
        flash_attn_mfma<1><<<ga, 256, 0, stream>>>(q_ws, k_ws, vt_ws, out,
                                                   nullptr, nullptr);
    }
}

// Round 10
// 128.631 us; speedup vs baseline: 2.9244x; 1.6766x over previous
//
#include <hip/hip_runtime.h>
#include <hip/hip_bf16.h>

// B=4, C=128, H=W=64 -> N=4096. ALL I/O FP32.
// Round 15: K-from-L2 attack. Flash is LDS-read-bound (R7: 32KB LDS read per
// wave-tile = 1024cy vs 256cy MFMA -> MfmaUtil 25%). All 4 waves read
// IDENTICAL kf fragments, so K never needs LDS: proj writes K in MFMA
// fragment order [tile32][ks][lane][8e]; flash loads kf as coalesced 1KB
// dwordx4 from L2 (K=1MB/batch, L2-resident), double-phase-early (softmax+PV
// slack > L2 latency). LDS halves to V-only 2x16KB; LDS traffic/MFMA halves.
// kf[2][8] regs are transient (R14's spill was PERSISTENT qa[2] blocking;
// R7 was ~168/256 unified, +64 transient fits). V keeps vmcnt(8) DMA dbuf.
// proj/combine = R11 proven (W-in-LDS); SPLIT=4.

#define BATCH 4
#define CH    128
#define NTOK  4096
#define TK    64
#define SCALE 0.08838834764831845f   // 1/sqrt(128)
#define LOG2E 1.4426950408889634f
#define MFIX  16.0f                  // fixed softmax offset (log2 units)

typedef __attribute__((ext_vector_type(8)))  short short8;
typedef __attribute__((ext_vector_type(4)))  float f32x4;
typedef __attribute__((ext_vector_type(16))) float f32x16;

static __device__ __forceinline__ unsigned short f2bf(float f) {
    __hip_bfloat16 h = (__hip_bfloat16)f;
    return *(const unsigned short*)&h;
}

static __device__ __forceinline__ unsigned cvt_pk_bf16(float lo, float hi) {
    unsigned r;
    asm("v_cvt_pk_bf16_f32 %0, %1, %2" : "=v"(r) : "v"(lo), "v"(hi));
    return r;
}

static __device__ __forceinline__ short8 pack_bf16x8(float4 a, float4 b) {
    union { unsigned u[4]; short8 s8; } f;
    f.u[0] = cvt_pk_bf16(a.x, a.y);
    f.u[1] = cvt_pk_bf16(a.z, a.w);
    f.u[2] = cvt_pk_bf16(b.x, b.y);
    f.u[3] = cvt_pk_bf16(b.z, b.w);
    return f.s8;
}

// ---------------- MFMA QKV projection (R11 W-in-LDS; K -> fragment order) --
// K fragment layout: ushort[B][NTOK/32][8(ks)][64(lane)][8(j)] where
// lane = (tok&31) + 32*((ch>>3)&1), ks = ch>>4, j = ch&7.
__global__ __launch_bounds__(256) void proj_mfma_kernel(
    const float* __restrict__ x,
    const float* __restrict__ Wq, const float* __restrict__ Wk,
    const float* __restrict__ Wv,
    const float* __restrict__ bq, const float* __restrict__ bk,
    const float* __restrict__ bv,
    unsigned short* __restrict__ q_ws, unsigned short* __restrict__ kf_ws,
    unsigned short* __restrict__ vt_ws)
{
    __shared__ __align__(16) unsigned short Wl[CH * CH];   // 32 KB, swizzled
    __shared__ __align__(16) unsigned short XsT[64 * CH];  // 16 KB, swizzled

    const int t    = threadIdx.x;
    const int w    = t >> 6;
    const int lane = t & 63;
    const int quad = lane >> 4;
    const int c16  = lane & 15;
    const int n0   = blockIdx.x * 64;
    const int b    = blockIdx.y;
    const int z    = blockIdx.z;          // 0=Q, 1=K, 2=V
    const float* xb = x + (size_t)b * CH * NTOK;
    const float* wm = (z == 0) ? Wq : (z == 1) ? Wk : Wv;

    #pragma unroll
    for (int i = 0; i < 8; ++i) {
        const int f   = i * 256 + t;
        const int row = f >> 4;
        const int u   = f & 15;
        const float* src = wm + f * 8;
        const float4 a = *(const float4*)src;
        const float4 c = *(const float4*)(src + 4);
        *(short8*)&Wl[row * CH + ((u ^ (row & 15)) << 3)] = pack_bf16x8(a, c);
    }
    {
        const int tok = lane;
        #pragma unroll
        for (int cc = 0; cc < 4; ++cc) {
            const int cb = 32 * w + 8 * cc;
            float xv[8];
            #pragma unroll
            for (int j = 0; j < 8; ++j)
                xv[j] = xb[(size_t)(cb + j) * NTOK + n0 + tok];
            union { unsigned u[4]; short8 s8; } pk;
            #pragma unroll
            for (int j = 0; j < 4; ++j)
                pk.u[j] = cvt_pk_bf16(xv[2 * j], xv[2 * j + 1]);
            const int phys = ((cb >> 3) ^ (tok & 15));
            *(short8*)&XsT[tok * CH + phys * 8] = pk.s8;
        }
    }
    __syncthreads();

    if (z < 2) {
        const float* bias = (z == 0) ? bq : bk;
        const float mul = (z == 0) ? (SCALE * LOG2E) : 1.0f;
        short8 xa[4];
        #pragma unroll
        for (int ks = 0; ks < 4; ++ks)
            xa[ks] = *(const short8*)&XsT[(16 * w + c16) * CH + (((4 * ks + quad) ^ c16) << 3)];
        #pragma unroll
        for (int nt = 0; nt < 8; ++nt) {
            f32x4 a = (f32x4){0.f, 0.f, 0.f, 0.f};
            #pragma unroll
            for (int ks = 0; ks < 4; ++ks) {
                const short8 bf = *(const short8*)
                    &Wl[(16 * nt + c16) * CH + (((4 * ks + quad) ^ c16) << 3)];
                a = __builtin_amdgcn_mfma_f32_16x16x32_bf16(xa[ks], bf, a, 0, 0, 0);
            }
            const float bvv = bias[16 * nt + c16];
            #pragma unroll
            for (int r = 0; r < 4; ++r) {
                const int n = n0 + 16 * w + quad * 4 + r;
                if (z == 0) {
                    q_ws[((size_t)b * NTOK + n) * CH + 16 * nt + c16] =
                        f2bf((a[r] + bvv) * mul);
                } else {
                    // K fragment-order write: ks=nt, half=(c16>>3), j=c16&7
                    const size_t idx =
                        (((size_t)b * (NTOK >> 5) + (n >> 5)) * 8 + nt) * 512
                        + ((n & 31) + 32 * (c16 >> 3)) * 8 + (c16 & 7);
                    kf_ws[idx] = f2bf(a[r] + bvv);
                }
            }
        }
    } else {
        #pragma unroll
        for (int nt = 0; nt < 4; ++nt) {
            short8 xbf[4];
            #pragma unroll
            for (int ks = 0; ks < 4; ++ks)
                xbf[ks] = *(const short8*)&XsT[(16 * nt + c16) * CH + (((4 * ks + quad) ^ c16) << 3)];
            #pragma unroll
            for (int mt = 0; mt < 2; ++mt) {
                const int crow16 = 16 * (2 * w + mt);
                f32x4 acc = (f32x4){0.f, 0.f, 0.f, 0.f};
                #pragma unroll
                for (int ks = 0; ks < 4; ++ks) {
                    const short8 wva = *(const short8*)
                        &Wl[(crow16 + c16) * CH + (((4 * ks + quad) ^ c16) << 3)];
                    acc = __builtin_amdgcn_mfma_f32_16x16x32_bf16(wva, xbf[ks], acc, 0, 0, 0);
                }
                #pragma unroll
                for (int r = 0; r < 4; ++r) {
                    const int crow = crow16 + quad * 4 + r;
                    vt_ws[((size_t)b * CH + crow) * NTOK + n0 + 16 * nt + c16] =
                        f2bf(acc[r] + bv[crow]);
                }
            }
        }
    }
}

// ---------------- split-KV flash: K from L2 (fragment loads), V in LDS -----
// 4 waves x 32 q-rows. Per tile: 16 coalesced 1KB kf loads (transient regs,
// issued a full phase early), V via global_load_lds dbuf + vmcnt(8).
template <int SPLIT>
__global__ __launch_bounds__(256, 2) void flash_attn_mfma(
    const unsigned short* __restrict__ q_ws,
    const unsigned short* __restrict__ kf_ws,
    const unsigned short* __restrict__ vt_ws,
    float* __restrict__ out,
    float* __restrict__ Op, float* __restrict__ l_p)
{
    __shared__ __align__(16) unsigned short VtU[2][CH * TK];  // 2 x 16 KB

    const int t    = threadIdx.x;
    const int w    = t >> 6;
    const int lane = t & 63;
    const int half = lane >> 5;
    const int l32  = lane & 31;
    const int jc   = blockIdx.y;
    const int b    = blockIdx.z;
    const int n0   = blockIdx.x * 128;
    const int jbeg = jc * (NTOK / SPLIT);
    constexpr int NT = (NTOK / SPLIT) / TK;
    static_assert(NT >= 2, "need at least 2 tiles");

    const unsigned short* kg = kf_ws + (size_t)b * NTOK * CH;  // fragment order
    const unsigned short* vg = vt_ws + (size_t)b * CH * NTOK;

    // Q B-frags: B[k=ch][n=q=l32]
    short8 qa[8];
    {
        const unsigned short* qrow =
            q_ws + ((size_t)b * NTOK + n0 + 32 * w + l32) * CH;
        #pragma unroll
        for (int ks = 0; ks < 8; ++ks)
            qa[ks] = *(const short8*)(qrow + ks * 16 + half * 8);
    }

    f32x16 Oa[4];  // O^T tiles, D[m=ch 32ct..][n=q]
    #pragma unroll
    for (int ct = 0; ct < 4; ++ct) Oa[ct] = (f32x16)(0.0f);
    float lsum = 0.f;

    const int vcl = lane >> 3, vu = lane & 7;

    auto V_DMA = [&](int buf, int jj) {
        #pragma unroll
        for (int ci = 0; ci < 4; ++ci) {
            const int c = 32 * w + 8 * ci + vcl;
            const int g = vu ^ (c & 7);
            const unsigned short* src = vg + (size_t)c * NTOK + jj + g * 8;
            __builtin_amdgcn_global_load_lds(
                (const __attribute__((address_space(1))) void*)src,
                (__attribute__((address_space(3))) void*)&VtU[buf][(32 * w + 8 * ci) * TK],
                16, 0, 0);
        }
    };

    // transient K fragments for one 64-token tile: 16 x 16B coalesced loads
    short8 kf[2][8];
    auto KF_LOAD = [&](int jj) {
        const unsigned short* kb = kg + (size_t)(jj >> 5) * 8 * 512;
        #pragma unroll
        for (int kt = 0; kt < 2; ++kt)
            #pragma unroll
            for (int ks = 0; ks < 8; ++ks)
                kf[kt][ks] = *(const short8*)(kb + ((kt * 8 + ks) * 64 + lane) * 8);
    };

    V_DMA(0, jbeg);    // 8 DMA in flight
    KF_LOAD(jbeg);     // 16 loads in flight

    int j0 = jbeg;
    for (int tt = 0; tt < NT; ++tt, j0 += TK) {
        const int cur = tt & 1;
        if (tt + 1 < NT) {
            V_DMA(cur ^ 1, j0 + TK);                         // prefetch next V
            // outstanding FIFO: V(t)[8], kf(t)[16], V(t+1)[8] -> keep last 8
            asm volatile("s_waitcnt vmcnt(8)" ::: "memory");
        } else {
            asm volatile("s_waitcnt vmcnt(0)" ::: "memory");
        }
        __builtin_amdgcn_sched_barrier(0);
        __builtin_amdgcn_s_barrier();                        // V(t) landed everywhere
        __builtin_amdgcn_sched_barrier(0);

        // --- S^T = K Q^T - MFIX from kf registers ---
        f32x16 s[2];
        s[0] = (f32x16)(-MFIX);
        s[1] = (f32x16)(-MFIX);
        #pragma unroll
        for (int ks = 0; ks < 8; ++ks) {
            s[0] = __builtin_amdgcn_mfma_f32_32x32x16_bf16(kf[0][ks], qa[ks], s[0], 0, 0, 0);
            s[1] = __builtin_amdgcn_mfma_f32_32x32x16_bf16(kf[1][ks], qa[ks], s[1], 0, 0, 0);
        }
        __builtin_amdgcn_sched_barrier(0);
        if (tt + 1 < NT) KF_LOAD(j0 + TK);   // reuse kf regs; QK^T consumed them
        __builtin_amdgcn_sched_barrier(0);

        // --- P = exp2(S) in-register; pack to PV B-frags (kf loads flying) ---
        short8 pb[4];
        #pragma unroll
        for (int kt = 0; kt < 2; ++kt) {
            float p[16];
            #pragma unroll
            for (int r = 0; r < 16; ++r) p[r] = exp2f(s[kt][r]);
            float a0 = 0.f, a1 = 0.f, a2 = 0.f, a3 = 0.f;
            #pragma unroll
            for (int r = 0; r < 4; ++r) {
                a0 += p[r]; a1 += p[4 + r]; a2 += p[8 + r]; a3 += p[12 + r];
            }
            lsum += (a0 + a1) + (a2 + a3);
            unsigned wd[8];
            #pragma unroll
            for (int i = 0; i < 8; ++i) wd[i] = cvt_pk_bf16(p[2 * i], p[2 * i + 1]);
            auto r02 = __builtin_amdgcn_permlane32_swap(wd[0], wd[2], false, false);
            auto r13 = __builtin_amdgcn_permlane32_swap(wd[1], wd[3], false, false);
            auto r46 = __builtin_amdgcn_permlane32_swap(wd[4], wd[6], false, false);
            auto r57 = __builtin_amdgcn_permlane32_swap(wd[5], wd[7], false, false);
            union { unsigned u[4]; short8 s8; } f0, f1;
            f0.u[0] = r02[0]; f0.u[1] = r13[0]; f0.u[2] = r02[1]; f0.u[3] = r13[1];
            f1.u[0] = r46[0]; f1.u[1] = r57[0]; f1.u[2] = r46[1]; f1.u[3] = r57[1];
            pb[2 * kt + 0] = f0.s8;
            pb[2 * kt + 1] = f1.s8;
        }

        // --- O^T += V^T P^T (V from LDS) ---
        #pragma unroll
        for (int ks2 = 0; ks2 < 4; ++ks2) {
            #pragma unroll
            for (int ct = 0; ct < 4; ++ct) {
                const int ch = 32 * ct + l32;
                const int ph = (2 * ks2 + half) ^ (ch & 7);
                const short8 vf = *(const short8*)&VtU[cur][ch * TK + ph * 8];
                Oa[ct] = __builtin_amdgcn_mfma_f32_32x32x16_bf16(vf, pb[ks2], Oa[ct], 0, 0, 0);
            }
        }
        __builtin_amdgcn_sched_barrier(0);
        __builtin_amdgcn_s_barrier();   // all waves done with VtU[cur] before re-stage
        __builtin_amdgcn_sched_barrier(0);
    }

    // --- epilogue: l lane-local; stores coalesced (lane = token) ---
    const float lt = lsum + __shfl_xor(lsum, 32);
    const int n = n0 + 32 * w + l32;

    if constexpr (SPLIT == 1) {
        const float inv = 1.0f / lt;
        #pragma unroll
        for (int ct = 0; ct < 4; ++ct) {
            #pragma unroll
            for (int r = 0; r < 16; ++r) {
                const int c = 32 * ct + (r & 3) + 8 * (r >> 2) + 4 * half;
                out[((size_t)b * CH + c) * NTOK + n] = Oa[ct][r] * inv;
            }
        }
    } else {
        const size_t chunk = (size_t)(b * SPLIT + jc);
        #pragma unroll
        for (int ct = 0; ct < 4; ++ct) {
            #pragma unroll
            for (int r = 0; r < 16; ++r) {
                const int c = 32 * ct + (r & 3) + 8 * (r >> 2) + 4 * half;
                Op[(chunk * CH + c) * NTOK + n] = Oa[ct][r];
            }
        }
        if (half == 0) l_p[chunk * NTOK + n] = lt;
    }
}

// ---------------- combine partials: Op layout [chunk][C][N], coalesced -----
template <int SPLIT>
__global__ __launch_bounds__(256) void combine_kernel(
    const float* __restrict__ Op, const float* __restrict__ l_p,
    float* __restrict__ out)
{
    const int b = blockIdx.y;
    const size_t idx = ((size_t)blockIdx.x * 256 + threadIdx.x) * 4;  // in C*N
    const int c = (int)(idx >> 12);           // / NTOK
    const int n = (int)(idx & (NTOK - 1));
    float4 acc = make_float4(0.f, 0.f, 0.f, 0.f);
    float4 den = make_float4(0.f, 0.f, 0.f, 0.f);
    #pragma unroll
    for (int j = 0; j < SPLIT; ++j) {
        const size_t chunk = (size_t)(b * SPLIT + j);
        const float4 o = *(const float4*)&Op[(chunk * CH + c) * NTOK + n];
        const float4 d = *(const float4*)&l_p[chunk * NTOK + n];
        acc.x += o.x; acc.y += o.y; acc.z += o.z; acc.w += o.w;
        den.x += d.x; den.y += d.y; den.z += d.z; den.w += d.w;
    }
    float4 r;
    r.x = acc.x / den.x; r.y = acc.y / den.y;
    r.z = acc.z / den.z; r.w = acc.w / den.w;
    *(float4*)&out[((size_t)b * CH * NTOK) + idx] = r;
}

extern "C" void kernel_launch(void* const* d_in, const int* in_sizes, int n_in,
                              void* d_out, int out_size, void* d_ws, size_t ws_size,
                              hipStream_t stream) {
    const float* x  = (const float*)d_in[0];
    const float* Wq = (const float*)d_in[1];
    const float* bq = (const float*)d_in[2];
    const float* Wk = (const float*)d_in[3];
    const float* bk = (const float*)d_in[4];
    const float* Wv = (const float*)d_in[5];
    const float* bv = (const float*)d_in[6];
    float* out = (float*)d_out;

    const size_t QKV = (size_t)BATCH * NTOK * CH;
    unsigned short* q_ws  = (unsigned short*)d_ws;
    unsigned short* kf_ws = q_ws + QKV;
    unsigned short* vt_ws = kf_ws + QKV;
    float* Op = (float*)(vt_ws + QKV);

    const size_t baseBytes = 3 * QKV * 2;
    auto needBytes = [&](size_t S) {
        return baseBytes + S * BATCH * NTOK * (size_t)(CH * 4 + 4);
    };

    dim3 gp(NTOK / 64, BATCH, 3);
    proj_mfma_kernel<<<gp, 256, 0, stream>>>(x, Wq, Wk, Wv, bq, bk, bv,
                                             q_ws, kf_ws, vt_ws);

    dim3 gc(CH * NTOK / 1024, BATCH);
    if (ws_size >= needBytes(4)) {
        float* l_p = Op + (size_t)4 * BATCH * NTOK * CH;
        dim3 ga(NTOK / 128, 4, BATCH);
        flash_attn_mfma<4><<<ga, 256, 0, stream>>>(q_ws, kf_ws, vt_ws, out, Op, l_p);
        combine_kernel<4><<<gc, 256, 0, stream>>>(Op, l_p, out);
    } else if (ws_size >= needBytes(2)) {
        float* l_p = Op + (size_t)2 * BATCH * NTOK * CH;
        dim3 ga(NTOK / 128, 2, BATCH);
        flash_attn_mfma<2><<<ga, 256, 0, stream>>>(q_ws, kf_ws, vt_ws, out, Op, l_p);
        combine_kernel<2><<<gc, 256, 0, stream>>>(Op, l_p, out);
    } else {
        dim3 ga(NTOK / 128, 1, BATCH);
        flash_attn_mfma<1><<<ga, 256, 0, stream>>>(q_ws, kf_ws, vt_ws, out,
                                                   nullptr, nullptr);
    }
}

// Round 11
// 126.552 us; speedup vs baseline: 2.9725x; 1.0164x over previous
//
#include <hip/hip_runtime.h>
#include <hip/hip_bf16.h>

// B=4, C=128, H=W=64 -> N=4096. ALL I/O FP32.
// Round 16: BARRIER-FREE flash. R15 refuted the LDS-BW theory (halved LDS
// traffic, duration unchanged); cycle model says ~65% of flash is stall at
// 2 waves/SIMD with 2 barriers/tile convoying the 4 waves. This round: K and
// V both in MFMA-fragment order in global (L2-resident), 32-token half-tiles,
// everything in registers -> ZERO LDS, ZERO barriers, ZERO manual waitcnt.
// Waves free-run; compiler inserts precise vmcnt; 2 waves/SIMD dephase and
// cover each other. XCD batch-affinity swizzle (batch b -> XCD pair {2b,2b+1},
// bijective) keeps each XCD's K+V working set (2MB) inside its 4MB L2.
// Reg peak ~204 < 256 cap. proj writes Q rows + K,V fragment arrays.

#define BATCH 4
#define CH    128
#define NTOK  4096
#define SCALE 0.08838834764831845f   // 1/sqrt(128)
#define LOG2E 1.4426950408889634f
#define MFIX  16.0f                  // fixed softmax offset (log2 units)

typedef __attribute__((ext_vector_type(8)))  short short8;
typedef __attribute__((ext_vector_type(4)))  float f32x4;
typedef __attribute__((ext_vector_type(16))) float f32x16;

static __device__ __forceinline__ unsigned short f2bf(float f) {
    __hip_bfloat16 h = (__hip_bfloat16)f;
    return *(const unsigned short*)&h;
}

static __device__ __forceinline__ unsigned cvt_pk_bf16(float lo, float hi) {
    unsigned r;
    asm("v_cvt_pk_bf16_f32 %0, %1, %2" : "=v"(r) : "v"(lo), "v"(hi));
    return r;
}

static __device__ __forceinline__ short8 pack_bf16x8(float4 a, float4 b) {
    union { unsigned u[4]; short8 s8; } f;
    f.u[0] = cvt_pk_bf16(a.x, a.y);
    f.u[1] = cvt_pk_bf16(a.z, a.w);
    f.u[2] = cvt_pk_bf16(b.x, b.y);
    f.u[3] = cvt_pk_bf16(b.z, b.w);
    return f.s8;
}

// ---------------- MFMA QKV projection (W-in-LDS; K,V -> fragment order) ----
// K frags: ushort[B][NTOK/32][8 ks][64 lane][8j], lane=(tok&31)+32*((ch>>3)&1),
//          ks=ch>>4, j=ch&7.   (verified R15)
// V frags: ushort[B][NTOK/32][2 g][4 ct][64 lane][8j], ct=ch>>5,
//          lane=(ch&31)+32*((tok>>3)&1), g=(tok>>4)&1, j=tok&7.
__global__ __launch_bounds__(256) void proj_mfma_kernel(
    const float* __restrict__ x,
    const float* __restrict__ Wq, const float* __restrict__ Wk,
    const float* __restrict__ Wv,
    const float* __restrict__ bq, const float* __restrict__ bk,
    const float* __restrict__ bv,
    unsigned short* __restrict__ q_ws, unsigned short* __restrict__ kf_ws,
    unsigned short* __restrict__ vf_ws)
{
    __shared__ __align__(16) unsigned short Wl[CH * CH];   // 32 KB, swizzled
    __shared__ __align__(16) unsigned short XsT[64 * CH];  // 16 KB, swizzled

    const int t    = threadIdx.x;
    const int w    = t >> 6;
    const int lane = t & 63;
    const int quad = lane >> 4;
    const int c16  = lane & 15;
    const int n0   = blockIdx.x * 64;
    const int b    = blockIdx.y;
    const int z    = blockIdx.z;          // 0=Q, 1=K, 2=V
    const float* xb = x + (size_t)b * CH * NTOK;
    const float* wm = (z == 0) ? Wq : (z == 1) ? Wk : Wv;

    #pragma unroll
    for (int i = 0; i < 8; ++i) {
        const int f   = i * 256 + t;
        const int row = f >> 4;
        const int u   = f & 15;
        const float* src = wm + f * 8;
        const float4 a = *(const float4*)src;
        const float4 c = *(const float4*)(src + 4);
        *(short8*)&Wl[row * CH + ((u ^ (row & 15)) << 3)] = pack_bf16x8(a, c);
    }
    {
        const int tok = lane;
        #pragma unroll
        for (int cc = 0; cc < 4; ++cc) {
            const int cb = 32 * w + 8 * cc;
            float xv[8];
            #pragma unroll
            for (int j = 0; j < 8; ++j)
                xv[j] = xb[(size_t)(cb + j) * NTOK + n0 + tok];
            union { unsigned u[4]; short8 s8; } pk;
            #pragma unroll
            for (int j = 0; j < 4; ++j)
                pk.u[j] = cvt_pk_bf16(xv[2 * j], xv[2 * j + 1]);
            const int phys = ((cb >> 3) ^ (tok & 15));
            *(short8*)&XsT[tok * CH + phys * 8] = pk.s8;
        }
    }
    __syncthreads();

    if (z < 2) {
        const float* bias = (z == 0) ? bq : bk;
        const float mul = (z == 0) ? (SCALE * LOG2E) : 1.0f;
        short8 xa[4];
        #pragma unroll
        for (int ks = 0; ks < 4; ++ks)
            xa[ks] = *(const short8*)&XsT[(16 * w + c16) * CH + (((4 * ks + quad) ^ c16) << 3)];
        #pragma unroll
        for (int nt = 0; nt < 8; ++nt) {
            f32x4 a = (f32x4){0.f, 0.f, 0.f, 0.f};
            #pragma unroll
            for (int ks = 0; ks < 4; ++ks) {
                const short8 bf = *(const short8*)
                    &Wl[(16 * nt + c16) * CH + (((4 * ks + quad) ^ c16) << 3)];
                a = __builtin_amdgcn_mfma_f32_16x16x32_bf16(xa[ks], bf, a, 0, 0, 0);
            }
            const float bvv = bias[16 * nt + c16];
            #pragma unroll
            for (int r = 0; r < 4; ++r) {
                const int n = n0 + 16 * w + quad * 4 + r;
                if (z == 0) {
                    q_ws[((size_t)b * NTOK + n) * CH + 16 * nt + c16] =
                        f2bf((a[r] + bvv) * mul);
                } else {
                    // K fragment write: ks=nt, lane=(n&31)+32*(c16>>3), j=c16&7
                    const size_t idx =
                        (((size_t)b * (NTOK >> 5) + (n >> 5)) * 8 + nt) * 512
                        + ((n & 31) + 32 * (c16 >> 3)) * 8 + (c16 & 7);
                    kf_ws[idx] = f2bf(a[r] + bvv);
                }
            }
        }
    } else {
        #pragma unroll
        for (int nt = 0; nt < 4; ++nt) {
            short8 xbf[4];
            #pragma unroll
            for (int ks = 0; ks < 4; ++ks)
                xbf[ks] = *(const short8*)&XsT[(16 * nt + c16) * CH + (((4 * ks + quad) ^ c16) << 3)];
            #pragma unroll
            for (int mt = 0; mt < 2; ++mt) {
                const int crow16 = 16 * (2 * w + mt);
                f32x4 acc = (f32x4){0.f, 0.f, 0.f, 0.f};
                #pragma unroll
                for (int ks = 0; ks < 4; ++ks) {
                    const short8 wva = *(const short8*)
                        &Wl[(crow16 + c16) * CH + (((4 * ks + quad) ^ c16) << 3)];
                    acc = __builtin_amdgcn_mfma_f32_16x16x32_bf16(wva, xbf[ks], acc, 0, 0, 0);
                }
                #pragma unroll
                for (int r = 0; r < 4; ++r) {
                    const int ch  = crow16 + quad * 4 + r;
                    const int tok = n0 + 16 * nt + c16;
                    // V fragment write
                    const size_t idx =
                        ((((size_t)b * (NTOK >> 5) + (tok >> 5)) * 2
                          + ((tok >> 4) & 1)) * 4 + (ch >> 5)) * 512
                        + ((ch & 31) + 32 * ((tok >> 3) & 1)) * 8 + (tok & 7);
                    vf_ws[idx] = f2bf(acc[r] + bv[ch]);
                }
            }
        }
    }
}

// ---------------- barrier-free split-KV flash: all operands from L2 --------
// 4 waves x 32 q-rows, fully independent (no LDS, no barriers). 32-token
// half-tiles: 8 kf + 8 vf coalesced 1KB loads, 8 QK^T + 8 PV MFMA, one
// 16-value in-register softmax. kf(t+1) prefetched after QK^T(t).
template <int SPLIT>
__global__ __launch_bounds__(256, 2) void flash_attn_mfma(
    const unsigned short* __restrict__ q_ws,
    const unsigned short* __restrict__ kf_ws,
    const unsigned short* __restrict__ vf_ws,
    float* __restrict__ out,
    float* __restrict__ Op, float* __restrict__ l_p)
{
    const int t    = threadIdx.x;
    const int w    = t >> 6;
    const int lane = t & 63;
    const int half = lane >> 5;
    const int l32  = lane & 31;

    int xx, jc, b;
    if constexpr (SPLIT == 4) {
        // bijective XCD batch-affinity swizzle: batch b -> XCDs {2b, 2b+1}
        const int bid = blockIdx.x;            // 0..511, XCD = bid & 7
        b = (bid & 7) >> 1;
        const int sub = ((bid & 1) << 6) | (bid >> 3);   // 0..127
        jc = sub >> 5;
        xx = sub & 31;
    } else {
        const int bid = blockIdx.x;
        xx = bid & 31;
        jc = (bid >> 5) % SPLIT;
        b  = bid / (32 * SPLIT);
    }

    const int n0   = xx * 128;
    const int jbeg = jc * (NTOK / SPLIT);
    constexpr int NT2 = (NTOK / SPLIT) / 32;   // 32-token half-tiles

    const unsigned short* kg = kf_ws + (size_t)b * NTOK * CH;
    const unsigned short* vg = vf_ws + (size_t)b * NTOK * CH;

    // Q B-frags: B[k=ch][n=q=l32]
    short8 qa[8];
    {
        const unsigned short* qrow =
            q_ws + ((size_t)b * NTOK + n0 + 32 * w + l32) * CH;
        #pragma unroll
        for (int ks = 0; ks < 8; ++ks)
            qa[ks] = *(const short8*)(qrow + ks * 16 + half * 8);
    }

    f32x16 Oa[4];  // O^T tiles, D[m=ch 32ct..][n=q]
    #pragma unroll
    for (int ct = 0; ct < 4; ++ct) Oa[ct] = (f32x16)(0.0f);
    float lsum = 0.f;

    short8 kf[8];
    auto KF_LOAD = [&](int jj) {
        const unsigned short* kb = kg + (size_t)(jj >> 5) * (8 * 512);
        #pragma unroll
        for (int ks = 0; ks < 8; ++ks)
            kf[ks] = *(const short8*)(kb + (ks * 64 + lane) * 8);
    };

    KF_LOAD(jbeg);

    int j0 = jbeg;
    for (int tt = 0; tt < NT2; ++tt, j0 += 32) {
        // --- S^T = K Q^T - MFIX (one 32x32 tile) ---
        f32x16 s = (f32x16)(-MFIX);
        #pragma unroll
        for (int ks = 0; ks < 8; ++ks)
            s = __builtin_amdgcn_mfma_f32_32x32x16_bf16(kf[ks], qa[ks], s, 0, 0, 0);

        // --- issue this tile's V fragments + next tile's K (kf regs free) ---
        short8 vfA[4], vfB[4];
        {
            const unsigned short* vb = vg + (size_t)(j0 >> 5) * (8 * 512);
            #pragma unroll
            for (int ct = 0; ct < 4; ++ct)
                vfA[ct] = *(const short8*)(vb + ((0 * 4 + ct) * 64 + lane) * 8);
            #pragma unroll
            for (int ct = 0; ct < 4; ++ct)
                vfB[ct] = *(const short8*)(vb + ((1 * 4 + ct) * 64 + lane) * 8);
        }
        if (tt + 1 < NT2) KF_LOAD(j0 + 32);

        // --- P = exp2(S); pack to PV B-frags via cvt_pk + permlane32_swap ---
        float p[16];
        #pragma unroll
        for (int r = 0; r < 16; ++r) p[r] = exp2f(s[r]);
        {
            float a0 = 0.f, a1 = 0.f, a2 = 0.f, a3 = 0.f;
            #pragma unroll
            for (int r = 0; r < 4; ++r) {
                a0 += p[r]; a1 += p[4 + r]; a2 += p[8 + r]; a3 += p[12 + r];
            }
            lsum += (a0 + a1) + (a2 + a3);
        }
        short8 pb0, pb1;
        {
            unsigned wd[8];
            #pragma unroll
            for (int i = 0; i < 8; ++i) wd[i] = cvt_pk_bf16(p[2 * i], p[2 * i + 1]);
            auto r02 = __builtin_amdgcn_permlane32_swap(wd[0], wd[2], false, false);
            auto r13 = __builtin_amdgcn_permlane32_swap(wd[1], wd[3], false, false);
            auto r46 = __builtin_amdgcn_permlane32_swap(wd[4], wd[6], false, false);
            auto r57 = __builtin_amdgcn_permlane32_swap(wd[5], wd[7], false, false);
            union { unsigned u[4]; short8 s8; } f0, f1;
            f0.u[0] = r02[0]; f0.u[1] = r13[0]; f0.u[2] = r02[1]; f0.u[3] = r13[1];
            f1.u[0] = r46[0]; f1.u[1] = r57[0]; f1.u[2] = r46[1]; f1.u[3] = r57[1];
            pb0 = f0.s8;
            pb1 = f1.s8;
        }

        // --- O^T += V^T P^T ---
        #pragma unroll
        for (int ct = 0; ct < 4; ++ct)
            Oa[ct] = __builtin_amdgcn_mfma_f32_32x32x16_bf16(vfA[ct], pb0, Oa[ct], 0, 0, 0);
        #pragma unroll
        for (int ct = 0; ct < 4; ++ct)
            Oa[ct] = __builtin_amdgcn_mfma_f32_32x32x16_bf16(vfB[ct], pb1, Oa[ct], 0, 0, 0);
    }

    // --- epilogue: l lane-local; stores coalesced (lane = token) ---
    const float lt = lsum + __shfl_xor(lsum, 32);
    const int n = n0 + 32 * w + l32;

    if constexpr (SPLIT == 1) {
        const float inv = 1.0f / lt;
        #pragma unroll
        for (int ct = 0; ct < 4; ++ct) {
            #pragma unroll
            for (int r = 0; r < 16; ++r) {
                const int c = 32 * ct + (r & 3) + 8 * (r >> 2) + 4 * half;
                out[((size_t)b * CH + c) * NTOK + n] = Oa[ct][r] * inv;
            }
        }
    } else {
        const size_t chunk = (size_t)(b * SPLIT + jc);
        #pragma unroll
        for (int ct = 0; ct < 4; ++ct) {
            #pragma unroll
            for (int r = 0; r < 16; ++r) {
                const int c = 32 * ct + (r & 3) + 8 * (r >> 2) + 4 * half;
                Op[(chunk * CH + c) * NTOK + n] = Oa[ct][r];
            }
        }
        if (half == 0) l_p[chunk * NTOK + n] = lt;
    }
}

// ---------------- combine partials: Op layout [chunk][C][N], coalesced -----
template <int SPLIT>
__global__ __launch_bounds__(256) void combine_kernel(
    const float* __restrict__ Op, const float* __restrict__ l_p,
    float* __restrict__ out)
{
    const int b = blockIdx.y;
    const size_t idx = ((size_t)blockIdx.x * 256 + threadIdx.x) * 4;  // in C*N
    const int c = (int)(idx >> 12);           // / NTOK
    const int n = (int)(idx & (NTOK - 1));
    float4 acc = make_float4(0.f, 0.f, 0.f, 0.f);
    float4 den = make_float4(0.f, 0.f, 0.f, 0.f);
    #pragma unroll
    for (int j = 0; j < SPLIT; ++j) {
        const size_t chunk = (size_t)(b * SPLIT + j);
        const float4 o = *(const float4*)&Op[(chunk * CH + c) * NTOK + n];
        const float4 d = *(const float4*)&l_p[chunk * NTOK + n];
        acc.x += o.x; acc.y += o.y; acc.z += o.z; acc.w += o.w;
        den.x += d.x; den.y += d.y; den.z += d.z; den.w += d.w;
    }
    float4 r;
    r.x = acc.x / den.x; r.y = acc.y / den.y;
    r.z = acc.z / den.z; r.w = acc.w / den.w;
    *(float4*)&out[((size_t)b * CH * NTOK) + idx] = r;
}

extern "C" void kernel_launch(void* const* d_in, const int* in_sizes, int n_in,
                              void* d_out, int out_size, void* d_ws, size_t ws_size,
                              hipStream_t stream) {
    const float* x  = (const float*)d_in[0];
    const float* Wq = (const float*)d_in[1];
    const float* bq = (const float*)d_in[2];
    const float* Wk = (const float*)d_in[3];
    const float* bk = (const float*)d_in[4];
    const float* Wv = (const float*)d_in[5];
    const float* bv = (const float*)d_in[6];
    float* out = (float*)d_out;

    const size_t QKV = (size_t)BATCH * NTOK * CH;
    unsigned short* q_ws  = (unsigned short*)d_ws;
    unsigned short* kf_ws = q_ws + QKV;
    unsigned short* vf_ws = kf_ws + QKV;
    float* Op = (float*)(vf_ws + QKV);

    const size_t baseBytes = 3 * QKV * 2;
    auto needBytes = [&](size_t S) {
        return baseBytes + S * BATCH * NTOK * (size_t)(CH * 4 + 4);
    };

    dim3 gp(NTOK / 64, BATCH, 3);
    proj_mfma_kernel<<<gp, 256, 0, stream>>>(x, Wq, Wk, Wv, bq, bk, bv,
                                             q_ws, kf_ws, vf_ws);

    dim3 gc(CH * NTOK / 1024, BATCH);
    if (ws_size >= needBytes(4)) {
        float* l_p = Op + (size_t)4 * BATCH * NTOK * CH;
        flash_attn_mfma<4><<<dim3(32 * 4 * BATCH), 256, 0, stream>>>(
            q_ws, kf_ws, vf_ws, out, Op, l_p);
        combine_kernel<4><<<gc, 256, 0, stream>>>(Op, l_p, out);
    } else {
        flash_attn_mfma<1><<<dim3(32 * BATCH), 256, 0, stream>>>(
            q_ws, kf_ws, vf_ws, out, nullptr, nullptr);
    }
}